// Round 5
// baseline (183.115 us; speedup 1.0000x reference)
//
#include <hip/hip_runtime.h>

typedef _Float16 half8 __attribute__((ext_vector_type(8)));
typedef _Float16 half4 __attribute__((ext_vector_type(4)));
typedef unsigned int uintx2 __attribute__((ext_vector_type(2)));
typedef unsigned int uintx4 __attribute__((ext_vector_type(4)));
typedef float floatx16 __attribute__((ext_vector_type(16)));

#define MFMA_F16(A, B, C) __builtin_amdgcn_mfma_f32_32x32x16_f16(A, B, C, 0, 0, 0)

constexpr int Bn = 4;     // batch
constexpr int Cc = 256;   // channels
constexpr int Cq = 32;    // C/8
constexpr int Nn = 4096;  // tokens (64*64)
constexpr float LOG2E = 1.44269504088896340736f;

// Layouts:
//   K4[b][cidx=0..3][n][8] : K fragment chunk cidx=(Cq>>3), dense across lanes
//   V8[b][nb=n>>3][c][8]   : V A-fragment, lane ml -> consecutive 16B chunks

__device__ inline floatx16 zero16() {
  floatx16 z;
#pragma unroll
  for (int i = 0; i < 16; ++i) z[i] = 0.f;
  return z;
}

__device__ inline unsigned int pkrtz(float a, float b) {
  return __builtin_bit_cast(unsigned int, __builtin_amdgcn_cvt_pkrtz(a, b));
}

// ---------------------------------------------------------------------------
// Kernel 0: W fp32 -> f16 (Wf scaled by log2e for exp2-domain softmax).
// ---------------------------------------------------------------------------
__global__ __launch_bounds__(256) void k_wconv(
    const float* __restrict__ Wf, const float* __restrict__ Wg,
    const float* __restrict__ Wh, _Float16* __restrict__ Wfh,
    _Float16* __restrict__ Wgh, _Float16* __restrict__ Whh) {
  int e = (blockIdx.x * 256 + threadIdx.x) * 4;
  const float* src;
  _Float16* dst;
  float sc = 1.f;
  if (e < 8192) { src = Wf + e; dst = Wfh + e; sc = LOG2E; }
  else if (e < 16384) { src = Wg + (e - 8192); dst = Wgh + (e - 8192); }
  else { src = Wh + (e - 16384); dst = Whh + (e - 16384); }
  float4 v = *(const float4*)src;
  half4 o;
  o[0] = (_Float16)(v.x * sc); o[1] = (_Float16)(v.y * sc);
  o[2] = (_Float16)(v.z * sc); o[3] = (_Float16)(v.w * sc);
  *(half4*)dst = o;
}

// ---------------------------------------------------------------------------
// Kernel 1: projections (unchanged from round 4).
// ---------------------------------------------------------------------------
__global__ __launch_bounds__(256) void k_proj(
    const float* __restrict__ x,
    const _Float16* __restrict__ Wfh, const float* __restrict__ bf,
    const _Float16* __restrict__ Wgh, const float* __restrict__ bg,
    const _Float16* __restrict__ Whh, const float* __restrict__ bh,
    _Float16* __restrict__ Q, _Float16* __restrict__ K4,
    _Float16* __restrict__ V8) {
  __shared__ float xs[32][260];  // pad 260: 16B-aligned rows, ~4-way on read
  int tid = threadIdx.x;
  int w = tid >> 6, lane = tid & 63;
  int ml = lane & 31, h = lane >> 5;
  int b = blockIdx.x >> 7, nt = blockIdx.x & 127;
  int n0 = nt * 32;

  // ---- stage x[b][0..255][n0..n0+31] transposed into xs[n_local][c] ----
  {
    int c = tid >> 3;          // 0..31
    int nl = (tid & 7) * 4;    // 4 consecutive tokens per thread
    const float* xp = x + (size_t)b * Cc * Nn + n0 + nl;
#pragma unroll
    for (int pass = 0; pass < 8; ++pass) {
      int cc = c + pass * 32;
      float4 v = *(const float4*)(xp + (size_t)cc * Nn);
      xs[nl + 0][cc] = v.x;
      xs[nl + 1][cc] = v.y;
      xs[nl + 2][cc] = v.z;
      xs[nl + 3][cc] = v.w;
    }
  }
  __syncthreads();

  // ---- build all 16 B-fragments once (lane ml = token n0+ml) ----
  half8 bfr[16];
#pragma unroll
  for (int kc = 0; kc < 16; ++kc) {
    const float* xp = &xs[ml][kc * 16 + h * 8];
    half8 f;
#pragma unroll
    for (int j = 0; j < 8; ++j) f[j] = (_Float16)xp[j];  // RTE
    bfr[kc] = f;
  }

  for (int t = w; t < 10; t += 4) {
    const _Float16* W;
    const float* bias;
    float bscale = 1.f;
    int o0 = 0;
    if (t == 0) { W = Wfh; bias = bf; bscale = LOG2E; }
    else if (t == 1) { W = Wgh; bias = bg; }
    else { W = Whh + (size_t)(t - 2) * 32 * Cc; bias = bh + (t - 2) * 32; o0 = (t - 2) * 32; }

    floatx16 acc = zero16();
    const _Float16* wp = W + (size_t)ml * Cc + h * 8;
#pragma unroll
    for (int kc = 0; kc < 16; ++kc) {
      half8 a = *(const half8*)(wp + kc * 16);
      acc = MFMA_F16(a, bfr[kc], acc);
    }

    if (t == 0) {
      // Q token-major Q[b][n][o]
      _Float16* op = Q + ((size_t)b * Nn + n0 + ml) * Cq;
#pragma unroll
      for (int qd = 0; qd < 4; ++qd) {
        float4 bq = *(const float4*)(bias + 8 * qd + 4 * h);
        const float* bqp = (const float*)&bq;
#pragma unroll
        for (int i = 0; i < 4; ++i) {
          int crow = i + 8 * qd + 4 * h;
          op[crow] = (_Float16)(acc[4 * qd + i] + bqp[i] * bscale);
        }
      }
    } else if (t == 1) {
      // K4[b][crow>>3][n][crow&7]
#pragma unroll
      for (int qd = 0; qd < 4; ++qd) {
        float4 bq = *(const float4*)(bias + 8 * qd + 4 * h);
        const float* bqp = (const float*)&bq;
#pragma unroll
        for (int i = 0; i < 4; ++i) {
          int crow = i + 8 * qd + 4 * h;
          K4[(((size_t)b * 4 + (crow >> 3)) * Nn + n0 + ml) * 8 + (crow & 7)] =
              (_Float16)(acc[4 * qd + i] + bqp[i]);
        }
      }
    } else {
      // V8[b][(n0+ml)>>3][c][ml&7]
      size_t nb = (size_t)((n0 + ml) >> 3);
      _Float16* op = V8 + (((size_t)b * 512 + nb) * 256) * 8 + (ml & 7);
#pragma unroll
      for (int qd = 0; qd < 4; ++qd) {
        float4 bq = *(const float4*)(bias + 8 * qd + 4 * h);
        const float* bqp = (const float*)&bq;
#pragma unroll
        for (int i = 0; i < 4; ++i) {
          int crow = i + 8 * qd + 4 * h;
          op[(size_t)(o0 + crow) * 8] = (_Float16)(acc[4 * qd + i] + bqp[i]);
        }
      }
    }
  }
}

// ---------------------------------------------------------------------------
// O-tree helpers: per-wave O tile (256c x 32m f32) <-> LDS region (32KB).
// Layout: float2 index ((cb*8+rp)*2 + h)*32 + ml  (2-way bank = free).
// ---------------------------------------------------------------------------
__device__ inline void otree_write(float2* dst, const floatx16* o) {
#pragma unroll
  for (int cb = 0; cb < 8; ++cb)
#pragma unroll
    for (int rp = 0; rp < 8; ++rp)
      dst[(cb * 8 + rp) * 64] = make_float2(o[cb][2 * rp], o[cb][2 * rp + 1]);
}

__device__ inline void otree_add(const float2* src, floatx16* o) {
#pragma unroll
  for (int cb = 0; cb < 8; ++cb)
#pragma unroll
    for (int rp = 0; rp < 8; ++rp) {
      float2 v = src[(cb * 8 + rp) * 64];
      o[cb][2 * rp] += v.x;
      o[cb][2 * rp + 1] += v.y;
    }
}

// ---------------------------------------------------------------------------
// Kernel 2: fused attention (round-5).
//  * pass-0 row max fused in (same MFMA operands/order as the old k_rowmax
//    => M bitwise identical => exp2(s-M) <= 1 invariant preserved)
//  * rotated software pipeline: exp2/pack(it) -> S-MFMA(it+1) -> PV(it);
//    K(it+1)/V(it) loads issued at body top so exp2 covers their latency
//  * s_setprio(1) around the PV MFMA cluster (unsynced waves regime)
// Register note: o[8] = 128 AGPR + ~110 VGPR -> 2 waves/SIMD; the win must
// come from in-wave ILP, which the rotation provides.
// ---------------------------------------------------------------------------
__global__ __launch_bounds__(512, 2) void k_attn(
    const _Float16* __restrict__ Q, const _Float16* __restrict__ K4,
    const _Float16* __restrict__ V8,
    const float* __restrict__ xin, const float* __restrict__ gamma,
    float* __restrict__ out) {
  __shared__ float Ored[4 * 8192];   // 4 tree regions x 32KB
  __shared__ float red[8][32];       // M reduce, then l reduce
  int tid = threadIdx.x, w = tid >> 6, lane = tid & 63;
  int ml = lane & 31, h = lane >> 5;
  int bx = blockIdx.x;
  int mt = bx & 127, b = bx >> 7;
  int m0 = mt * 32;

  const _Float16* qp = Q + ((size_t)b * Nn + m0 + ml) * Cq + h * 8;
  half8 qb0 = *(const half8*)(qp);
  half8 qb1 = *(const half8*)(qp + 16);
  float g = gamma[0];

  // K fragments: n = it*256 + w*32 + ml (coalesced across ml)
  const _Float16* k4b0 = K4 + (((size_t)b * 4 + h) * Nn + w * 32 + ml) * 8;
  const _Float16* k4b1 = K4 + (((size_t)b * 4 + 2 + h) * Nn + w * 32 + ml) * 8;
  // V8: nb = it*32 + w*4 + kc*2 + h ; element ((b*512+nb)*256 + c)*8
  const _Float16* v8b = V8 + (((size_t)b * 512 + w * 4 + h) * 256 + ml) * 8;

  // ---- pass 0: row max over this wave's n-slices (replaces k_rowmax) ----
  float mx = -3.0e38f;
  {
    half8 a0 = *(const half8*)(k4b0);
    half8 a1 = *(const half8*)(k4b1);
    for (int it = 0; it < 16; ++it) {
      floatx16 s = zero16();
      s = MFMA_F16(a0, qb0, s);
      s = MFMA_F16(a1, qb1, s);
      // prefetch next (it=15 overruns into V8 region: benign)
      a0 = *(const half8*)(k4b0 + (size_t)(it + 1) * 2048);
      a1 = *(const half8*)(k4b1 + (size_t)(it + 1) * 2048);
#pragma unroll
      for (int i = 0; i < 16; ++i) mx = fmaxf(mx, s[i]);
    }
  }
  mx = fmaxf(mx, __shfl_xor(mx, 32, 64));
  if (h == 0) red[w][ml] = mx;
  __syncthreads();
  float Mv = red[0][ml];
#pragma unroll
  for (int i = 1; i < 8; ++i) Mv = fmaxf(Mv, red[i][ml]);
  __syncthreads();   // red reused for l later

  // ---- main loop: rotated pipeline ----
  floatx16 o[8];
#pragma unroll
  for (int i = 0; i < 8; ++i) o[i] = zero16();
  float lacc = 0.f;

  floatx16 s;
  {
    half8 k0 = *(const half8*)(k4b0);
    half8 k1 = *(const half8*)(k4b1);
    s = zero16();
    s = MFMA_F16(k0, qb0, s);
    s = MFMA_F16(k1, qb1, s);
  }

  for (int it = 0; it < 16; ++it) {
    const _Float16* vp = v8b + (size_t)it * 65536;  // 32 nb * 256c * 8
    // issue independent loads first: V(it) partial prefetch + K(it+1)
    half8 va[4];
#pragma unroll
    for (int cb = 0; cb < 4; ++cb) va[cb] = *(const half8*)(vp + cb * 256);
    half8 kn0 = *(const half8*)(k4b0 + (size_t)(it + 1) * 2048);  // it=15: benign overrun
    half8 kn1 = *(const half8*)(k4b1 + (size_t)(it + 1) * 2048);
    // ---- softmax numerator from s(it) ----
    float p[16];
#pragma unroll
    for (int i = 0; i < 16; ++i) p[i] = __builtin_amdgcn_exp2f(s[i] - Mv);
#pragma unroll
    for (int i = 0; i < 16; ++i) lacc += p[i];
    unsigned int c0 = pkrtz(p[0], p[1]),  c1 = pkrtz(p[2], p[3]);
    unsigned int c2 = pkrtz(p[4], p[5]),  c3 = pkrtz(p[6], p[7]);
    unsigned int c4 = pkrtz(p[8], p[9]),  c5 = pkrtz(p[10], p[11]);
    unsigned int c6 = pkrtz(p[12], p[13]), c7 = pkrtz(p[14], p[15]);
    uintx2 t02 = __builtin_amdgcn_permlane32_swap(c0, c2, false, false);
    uintx2 t13 = __builtin_amdgcn_permlane32_swap(c1, c3, false, false);
    uintx2 t46 = __builtin_amdgcn_permlane32_swap(c4, c6, false, false);
    uintx2 t57 = __builtin_amdgcn_permlane32_swap(c5, c7, false, false);
    uintx4 f0v = {t02.x, t13.x, t02.y, t13.y};   // n-offsets  0..15
    uintx4 f1v = {t46.x, t57.x, t46.y, t57.y};   // n-offsets 16..31
    half8 pf0 = __builtin_bit_cast(half8, f0v);
    half8 pf1 = __builtin_bit_cast(half8, f1v);
    // ---- issue next-iter S before PV so its result lands during PV ----
    floatx16 sn = zero16();
    sn = MFMA_F16(kn0, qb0, sn);
    sn = MFMA_F16(kn1, qb1, sn);
    // ---- PV: all 256 channels for this n-slice ----
    __builtin_amdgcn_s_setprio(1);
#pragma unroll
    for (int cb = 0; cb < 4; ++cb) o[cb] = MFMA_F16(va[cb], pf0, o[cb]);
#pragma unroll
    for (int cb = 4; cb < 8; ++cb) {
      half8 vf = *(const half8*)(vp + cb * 256);
      o[cb] = MFMA_F16(vf, pf0, o[cb]);
    }
#pragma unroll
    for (int cb = 0; cb < 8; ++cb) {
      half8 vf = *(const half8*)(vp + 4096 + cb * 256);
      o[cb] = MFMA_F16(vf, pf1, o[cb]);
    }
    __builtin_amdgcn_s_setprio(0);
    s = sn;
  }

  // ---- l partials ----
  lacc += __shfl_xor(lacc, 32, 64);
  if (h == 0) red[w][ml] = lacc;

  // ---- O tree reduction across 8 n-slice waves ----
  float2* Ored2 = (float2*)Ored;
  int lofs = h * 32 + ml;
  if (w >= 4) otree_write(Ored2 + (w - 4) * 4096 + lofs, o);
  __syncthreads();
  if (w < 4) otree_add(Ored2 + w * 4096 + lofs, o);
  __syncthreads();
  if (w == 2 || w == 3) otree_write(Ored2 + (w - 2) * 4096 + lofs, o);
  __syncthreads();
  if (w < 2) otree_add(Ored2 + w * 4096 + lofs, o);
  __syncthreads();
  if (w == 1) otree_write(Ored2 + lofs, o);
  __syncthreads();
  if (w == 0) { otree_add(Ored2 + lofs, o); otree_write(Ored2 + lofs, o); }
  __syncthreads();

  // ---- fused epilogue: wave w handles channel block cb = w ----
  float lv = 0.f;
#pragma unroll
  for (int i = 0; i < 8; ++i) lv += red[i][ml];
  float scale = g / lv;
  const float2* src = Ored2 + lofs;
  size_t obase = ((size_t)b * 256 + w * 32) * (size_t)Nn + m0 + ml;
#pragma unroll
  for (int rp = 0; rp < 8; ++rp) {
    float2 v = src[(w * 8 + rp) * 64];
    int r = 2 * rp;
    int cA = (r & 3) + 8 * (r >> 2) + 4 * h;
    size_t oa = obase + (size_t)cA * Nn;
    out[oa] = scale * v.x + xin[oa];
    out[oa + Nn] = scale * v.y + xin[oa + Nn];
  }
}

// ---------------------------------------------------------------------------
extern "C" void kernel_launch(void* const* d_in, const int* in_sizes, int n_in,
                              void* d_out, int out_size, void* d_ws,
                              size_t ws_size, hipStream_t stream) {
  const float* x = (const float*)d_in[0];
  const float* Wf = (const float*)d_in[1];
  const float* bf = (const float*)d_in[2];
  const float* Wg = (const float*)d_in[3];
  const float* bg = (const float*)d_in[4];
  const float* Wh = (const float*)d_in[5];
  const float* bh = (const float*)d_in[6];
  const float* gamma = (const float*)d_in[7];
  float* out = (float*)d_out;

  char* ws = (char*)d_ws;
  // Layout (bytes):
  //   Q      [0,        1048576)
  //   K4     [1048576,  2097152)
  //   V8     [2097152, 10485760)
  //   Wfh    [10551296, 10567680)
  //   Wgh    [10567680, 10584064)
  //   Whh    [10584064, 10715136)
  _Float16* Q  = (_Float16*)(ws);
  _Float16* K4 = (_Float16*)(ws + 1048576);
  _Float16* V8 = (_Float16*)(ws + 2097152);
  _Float16* Wfh = (_Float16*)(ws + 10551296);
  _Float16* Wgh = (_Float16*)(ws + 10567680);
  _Float16* Whh = (_Float16*)(ws + 10584064);

  k_wconv<<<dim3(80), dim3(256), 0, stream>>>(Wf, Wg, Wh, Wfh, Wgh, Whh);
  k_proj<<<dim3(512), dim3(256), 0, stream>>>(x, Wfh, bf, Wgh, bg, Whh, bh, Q, K4, V8);
  k_attn<<<dim3(512), dim3(512), 0, stream>>>(Q, K4, V8, x, gamma, out);
}

// Round 6
// 167.809 us; speedup vs baseline: 1.0912x; 1.0912x over previous
//
#include <hip/hip_runtime.h>

typedef _Float16 half8 __attribute__((ext_vector_type(8)));
typedef _Float16 half4 __attribute__((ext_vector_type(4)));
typedef unsigned int uintx2 __attribute__((ext_vector_type(2)));
typedef unsigned int uintx4 __attribute__((ext_vector_type(4)));
typedef float floatx16 __attribute__((ext_vector_type(16)));

#define MFMA_F16(A, B, C) __builtin_amdgcn_mfma_f32_32x32x16_f16(A, B, C, 0, 0, 0)

constexpr int Bn = 4;     // batch
constexpr int Cc = 256;   // channels
constexpr int Cq = 32;    // C/8
constexpr int Nn = 4096;  // tokens (64*64)
constexpr float LOG2E = 1.44269504088896340736f;

// Layouts:
//   K4[b][cidx=0..3][n][8] : K fragment chunk cidx=(Cq>>3), dense across lanes
//   V8[b][nb=n>>3][c][8]   : V A-fragment, lane ml -> consecutive 16B chunks

__device__ inline floatx16 zero16() {
  floatx16 z;
#pragma unroll
  for (int i = 0; i < 16; ++i) z[i] = 0.f;
  return z;
}

__device__ inline unsigned int pkrtz(float a, float b) {
  return __builtin_bit_cast(unsigned int, __builtin_amdgcn_cvt_pkrtz(a, b));
}

// ---------------------------------------------------------------------------
// Kernel 0: W fp32 -> f16 (Wf scaled by log2e for exp2-domain softmax).
// ---------------------------------------------------------------------------
__global__ __launch_bounds__(256) void k_wconv(
    const float* __restrict__ Wf, const float* __restrict__ Wg,
    const float* __restrict__ Wh, _Float16* __restrict__ Wfh,
    _Float16* __restrict__ Wgh, _Float16* __restrict__ Whh) {
  int e = (blockIdx.x * 256 + threadIdx.x) * 4;
  const float* src;
  _Float16* dst;
  float sc = 1.f;
  if (e < 8192) { src = Wf + e; dst = Wfh + e; sc = LOG2E; }
  else if (e < 16384) { src = Wg + (e - 8192); dst = Wgh + (e - 8192); }
  else { src = Wh + (e - 16384); dst = Whh + (e - 16384); }
  float4 v = *(const float4*)src;
  half4 o;
  o[0] = (_Float16)(v.x * sc); o[1] = (_Float16)(v.y * sc);
  o[2] = (_Float16)(v.z * sc); o[3] = (_Float16)(v.w * sc);
  *(half4*)dst = o;
}

// ---------------------------------------------------------------------------
// Kernel 1: projections. Round-6 change: 8 waves per 32-token block (512 thr)
// instead of 4 -- halves the serial t-tile depth per wave (1-2 tiles instead
// of 2-3). Staging re-mapped to 4 passes/thread. Store patterns unchanged.
// ---------------------------------------------------------------------------
__global__ __launch_bounds__(512) void k_proj(
    const float* __restrict__ x,
    const _Float16* __restrict__ Wfh, const float* __restrict__ bf,
    const _Float16* __restrict__ Wgh, const float* __restrict__ bg,
    const _Float16* __restrict__ Whh, const float* __restrict__ bh,
    _Float16* __restrict__ Q, _Float16* __restrict__ K4,
    _Float16* __restrict__ V8) {
  __shared__ float xs[32][260];  // pad 260: 16B-aligned rows, ~4-way on read
  int tid = threadIdx.x;
  int w = tid >> 6, lane = tid & 63;
  int ml = lane & 31, h = lane >> 5;
  int b = blockIdx.x >> 7, nt = blockIdx.x & 127;
  int n0 = nt * 32;

  // ---- stage x[b][0..255][n0..n0+31] transposed into xs[n_local][c] ----
  {
    int c = tid >> 3;          // 0..63
    int nl = (tid & 7) * 4;    // 4 consecutive tokens per thread
    const float* xp = x + (size_t)b * Cc * Nn + n0 + nl;
#pragma unroll
    for (int pass = 0; pass < 4; ++pass) {
      int cc = c + pass * 64;
      float4 v = *(const float4*)(xp + (size_t)cc * Nn);
      xs[nl + 0][cc] = v.x;
      xs[nl + 1][cc] = v.y;
      xs[nl + 2][cc] = v.z;
      xs[nl + 3][cc] = v.w;
    }
  }
  __syncthreads();

  // ---- build all 16 B-fragments once (lane ml = token n0+ml) ----
  half8 bfr[16];
#pragma unroll
  for (int kc = 0; kc < 16; ++kc) {
    const float* xp = &xs[ml][kc * 16 + h * 8];
    half8 f;
#pragma unroll
    for (int j = 0; j < 8; ++j) f[j] = (_Float16)xp[j];  // RTE
    bfr[kc] = f;
  }

  for (int t = w; t < 10; t += 8) {
    const _Float16* W;
    const float* bias;
    float bscale = 1.f;
    int o0 = 0;
    if (t == 0) { W = Wfh; bias = bf; bscale = LOG2E; }
    else if (t == 1) { W = Wgh; bias = bg; }
    else { W = Whh + (size_t)(t - 2) * 32 * Cc; bias = bh + (t - 2) * 32; o0 = (t - 2) * 32; }

    floatx16 acc = zero16();
    const _Float16* wp = W + (size_t)ml * Cc + h * 8;
#pragma unroll
    for (int kc = 0; kc < 16; ++kc) {
      half8 a = *(const half8*)(wp + kc * 16);
      acc = MFMA_F16(a, bfr[kc], acc);
    }

    if (t == 0) {
      // Q token-major Q[b][n][o]
      _Float16* op = Q + ((size_t)b * Nn + n0 + ml) * Cq;
#pragma unroll
      for (int qd = 0; qd < 4; ++qd) {
        float4 bq = *(const float4*)(bias + 8 * qd + 4 * h);
        const float* bqp = (const float*)&bq;
#pragma unroll
        for (int i = 0; i < 4; ++i) {
          int crow = i + 8 * qd + 4 * h;
          op[crow] = (_Float16)(acc[4 * qd + i] + bqp[i] * bscale);
        }
      }
    } else if (t == 1) {
      // K4[b][crow>>3][n][crow&7]
#pragma unroll
      for (int qd = 0; qd < 4; ++qd) {
        float4 bq = *(const float4*)(bias + 8 * qd + 4 * h);
        const float* bqp = (const float*)&bq;
#pragma unroll
        for (int i = 0; i < 4; ++i) {
          int crow = i + 8 * qd + 4 * h;
          K4[(((size_t)b * 4 + (crow >> 3)) * Nn + n0 + ml) * 8 + (crow & 7)] =
              (_Float16)(acc[4 * qd + i] + bqp[i]);
        }
      }
    } else {
      // V8[b][(n0+ml)>>3][c][ml&7]
      size_t nb = (size_t)((n0 + ml) >> 3);
      _Float16* op = V8 + (((size_t)b * 512 + nb) * 256) * 8 + (ml & 7);
#pragma unroll
      for (int qd = 0; qd < 4; ++qd) {
        float4 bq = *(const float4*)(bias + 8 * qd + 4 * h);
        const float* bqp = (const float*)&bq;
#pragma unroll
        for (int i = 0; i < 4; ++i) {
          int crow = i + 8 * qd + 4 * h;
          op[(size_t)(o0 + crow) * 8] = (_Float16)(acc[4 * qd + i] + bqp[i]);
        }
      }
    }
  }
}

// ---------------------------------------------------------------------------
// Kernel 2: pass-1 row max (log2-domain), K4 coalesced loads.
// MFMA bitwise identical to k_attn's S -> exp2(s-M) <= 1 exactly.
// ---------------------------------------------------------------------------
__global__ __launch_bounds__(512) void k_rowmax(const _Float16* __restrict__ Q,
                                                const _Float16* __restrict__ K4,
                                                float* __restrict__ M) {
  __shared__ float red[8][32];
  int tid = threadIdx.x, w = tid >> 6, lane = tid & 63;
  int ml = lane & 31, h = lane >> 5;
  int b = blockIdx.x >> 7, mt = blockIdx.x & 127;
  int m0 = mt * 32;
  const _Float16* qp = Q + ((size_t)b * Nn + m0 + ml) * Cq + h * 8;
  half8 qb0 = *(const half8*)(qp);
  half8 qb1 = *(const half8*)(qp + 16);
  const _Float16* kp0 = K4 + (((size_t)b * 4 + h) * Nn + w * 512 + ml) * 8;
  const _Float16* kp1 = K4 + (((size_t)b * 4 + 2 + h) * Nn + w * 512 + ml) * 8;
  float mx = -3.0e38f;
  for (int t = 0; t < 16; ++t) {
    floatx16 s = zero16();
    half8 k0 = *(const half8*)(kp0 + (size_t)t * 32 * 8);
    half8 k1 = *(const half8*)(kp1 + (size_t)t * 32 * 8);
    s = MFMA_F16(k0, qb0, s);
    s = MFMA_F16(k1, qb1, s);
#pragma unroll
    for (int i = 0; i < 16; ++i) mx = fmaxf(mx, s[i]);
  }
  mx = fmaxf(mx, __shfl_xor(mx, 32, 64));
  if (h == 0) red[w][ml] = mx;
  __syncthreads();
  if (tid < 32) {
    float m2 = red[0][tid];
#pragma unroll
    for (int i = 1; i < 8; ++i) m2 = fmaxf(m2, red[i][tid]);
    M[(size_t)b * Nn + m0 + tid] = m2;
  }
}

// ---------------------------------------------------------------------------
// O-tree helpers: per-wave O tile (256c x 32m f32) <-> LDS region (32KB).
// Layout: float2 index ((cb*8+rp)*2 + h)*32 + ml  (2-way bank = free).
// ---------------------------------------------------------------------------
__device__ inline void otree_write(float2* dst, const floatx16* o) {
#pragma unroll
  for (int cb = 0; cb < 8; ++cb)
#pragma unroll
    for (int rp = 0; rp < 8; ++rp)
      dst[(cb * 8 + rp) * 64] = make_float2(o[cb][2 * rp], o[cb][2 * rp + 1]);
}

__device__ inline void otree_add(const float2* src, floatx16* o) {
#pragma unroll
  for (int cb = 0; cb < 8; ++cb)
#pragma unroll
    for (int rp = 0; rp < 8; ++rp) {
      float2 v = src[(cb * 8 + rp) * 64];
      o[cb][2 * rp] += v.x;
      o[cb][2 * rp + 1] += v.y;
    }
}

// ---------------------------------------------------------------------------
// Kernel 3: attention -- exact round-4 structure (best total). Block = 32
// m-rows, 8 waves = 8 n-slices, P handed S->PV via cvt_pkrtz+permlane32_swap
// in registers (no main-loop LDS/barrier), LDS tree-reduce of O partials,
// fused epilogue (gamma*O/l + x). M from k_rowmax (same MFMA => exp2<=1).
// ---------------------------------------------------------------------------
__global__ __launch_bounds__(512, 2) void k_attn(
    const _Float16* __restrict__ Q, const _Float16* __restrict__ K4,
    const _Float16* __restrict__ V8, const float* __restrict__ M,
    const float* __restrict__ xin, const float* __restrict__ gamma,
    float* __restrict__ out) {
  __shared__ float Ored[4 * 8192];   // 4 tree regions x 32KB
  __shared__ float lred[8][32];
  int tid = threadIdx.x, w = tid >> 6, lane = tid & 63;
  int ml = lane & 31, h = lane >> 5;
  int bx = blockIdx.x;
  int mt = bx & 127, b = bx >> 7;
  int m0 = mt * 32;

  const _Float16* qp = Q + ((size_t)b * Nn + m0 + ml) * Cq + h * 8;
  half8 qb0 = *(const half8*)(qp);
  half8 qb1 = *(const half8*)(qp + 16);
  float Mv = M[(size_t)b * Nn + m0 + ml];
  float g = gamma[0];
  float lacc = 0.f;

  // K fragments: n = it*256 + w*32 + ml (coalesced across ml)
  const _Float16* k4b0 = K4 + (((size_t)b * 4 + h) * Nn + w * 32 + ml) * 8;
  const _Float16* k4b1 = K4 + (((size_t)b * 4 + 2 + h) * Nn + w * 32 + ml) * 8;
  // V8: nb = it*32 + w*4 + kc*2 + h ; element ((b*512+nb)*256 + c)*8
  const _Float16* v8b = V8 + (((size_t)b * 512 + w * 4 + h) * 256 + ml) * 8;

  floatx16 o[8];
#pragma unroll
  for (int i = 0; i < 8; ++i) o[i] = zero16();

  half8 k0 = *(const half8*)(k4b0);
  half8 k1 = *(const half8*)(k4b1);

  for (int it = 0; it < 16; ++it) {
    // ---- S: 32m x 32n for this wave's n-slice ----
    floatx16 s = zero16();
    s = MFMA_F16(k0, qb0, s);
    s = MFMA_F16(k1, qb1, s);
    // prefetch next iter's K (it=15 overruns into V8 region: benign)
    k0 = *(const half8*)(k4b0 + (size_t)(it + 1) * 2048);
    k1 = *(const half8*)(k4b1 + (size_t)(it + 1) * 2048);
    // ---- softmax numerator, in-register pack + half-swap ----
    float p[16];
#pragma unroll
    for (int i = 0; i < 16; ++i) p[i] = __builtin_amdgcn_exp2f(s[i] - Mv);
#pragma unroll
    for (int i = 0; i < 16; ++i) lacc += p[i];
    unsigned int c0 = pkrtz(p[0], p[1]),  c1 = pkrtz(p[2], p[3]);
    unsigned int c2 = pkrtz(p[4], p[5]),  c3 = pkrtz(p[6], p[7]);
    unsigned int c4 = pkrtz(p[8], p[9]),  c5 = pkrtz(p[10], p[11]);
    unsigned int c6 = pkrtz(p[12], p[13]), c7 = pkrtz(p[14], p[15]);
    // newD = [D(0:31) | S(0:31)], newS = [D(32:63) | S(32:63)]
    uintx2 t02 = __builtin_amdgcn_permlane32_swap(c0, c2, false, false);
    uintx2 t13 = __builtin_amdgcn_permlane32_swap(c1, c3, false, false);
    uintx2 t46 = __builtin_amdgcn_permlane32_swap(c4, c6, false, false);
    uintx2 t57 = __builtin_amdgcn_permlane32_swap(c5, c7, false, false);
    uintx4 f0v = {t02.x, t13.x, t02.y, t13.y};   // n-offsets  0..15 (k = h*8+j)
    uintx4 f1v = {t46.x, t57.x, t46.y, t57.y};   // n-offsets 16..31
    half8 pf0 = __builtin_bit_cast(half8, f0v);
    half8 pf1 = __builtin_bit_cast(half8, f1v);
    // ---- PV: all 256 channels for this n-slice ----
    const _Float16* vp = v8b + (size_t)it * 65536;  // 32 nb * 256c * 8
#pragma unroll
    for (int cb = 0; cb < 8; ++cb) {
      half8 vf0 = *(const half8*)(vp + cb * 256);
      o[cb] = MFMA_F16(vf0, pf0, o[cb]);
    }
#pragma unroll
    for (int cb = 0; cb < 8; ++cb) {
      half8 vf1 = *(const half8*)(vp + 4096 + cb * 256);
      o[cb] = MFMA_F16(vf1, pf1, o[cb]);
    }
  }

  // ---- l partials ----
  lacc += __shfl_xor(lacc, 32, 64);
  if (h == 0) lred[w][ml] = lacc;

  // ---- O tree reduction across 8 n-slice waves ----
  float2* Ored2 = (float2*)Ored;
  int lofs = h * 32 + ml;
  if (w >= 4) otree_write(Ored2 + (w - 4) * 4096 + lofs, o);
  __syncthreads();
  if (w < 4) otree_add(Ored2 + w * 4096 + lofs, o);
  __syncthreads();
  if (w == 2 || w == 3) otree_write(Ored2 + (w - 2) * 4096 + lofs, o);
  __syncthreads();
  if (w < 2) otree_add(Ored2 + w * 4096 + lofs, o);
  __syncthreads();
  if (w == 1) otree_write(Ored2 + lofs, o);
  __syncthreads();
  if (w == 0) { otree_add(Ored2 + lofs, o); otree_write(Ored2 + lofs, o); }
  __syncthreads();

  // ---- fused epilogue: wave w handles channel block cb = w ----
  float lv = 0.f;
#pragma unroll
  for (int i = 0; i < 8; ++i) lv += lred[i][ml];
  float scale = g / lv;
  const float2* src = Ored2 + lofs;
  size_t obase = ((size_t)b * 256 + w * 32) * (size_t)Nn + m0 + ml;
#pragma unroll
  for (int rp = 0; rp < 8; ++rp) {
    float2 v = src[(w * 8 + rp) * 64];
    int r = 2 * rp;
    int cA = (r & 3) + 8 * (r >> 2) + 4 * h;
    size_t oa = obase + (size_t)cA * Nn;
    out[oa] = scale * v.x + xin[oa];
    out[oa + Nn] = scale * v.y + xin[oa + Nn];
  }
}

// ---------------------------------------------------------------------------
extern "C" void kernel_launch(void* const* d_in, const int* in_sizes, int n_in,
                              void* d_out, int out_size, void* d_ws,
                              size_t ws_size, hipStream_t stream) {
  const float* x = (const float*)d_in[0];
  const float* Wf = (const float*)d_in[1];
  const float* bf = (const float*)d_in[2];
  const float* Wg = (const float*)d_in[3];
  const float* bg = (const float*)d_in[4];
  const float* Wh = (const float*)d_in[5];
  const float* bh = (const float*)d_in[6];
  const float* gamma = (const float*)d_in[7];
  float* out = (float*)d_out;

  char* ws = (char*)d_ws;
  // Layout (bytes):
  //   Q      [0,        1048576)
  //   K4     [1048576,  2097152)
  //   V8     [2097152, 10485760)
  //   M      [10485760, 10551296)
  //   Wfh    [10551296, 10567680)
  //   Wgh    [10567680, 10584064)
  //   Whh    [10584064, 10715136)
  _Float16* Q  = (_Float16*)(ws);
  _Float16* K4 = (_Float16*)(ws + 1048576);
  _Float16* V8 = (_Float16*)(ws + 2097152);
  float*    M  = (float*)   (ws + 10485760);
  _Float16* Wfh = (_Float16*)(ws + 10551296);
  _Float16* Wgh = (_Float16*)(ws + 10567680);
  _Float16* Whh = (_Float16*)(ws + 10584064);

  k_wconv<<<dim3(80), dim3(256), 0, stream>>>(Wf, Wg, Wh, Wfh, Wgh, Whh);
  k_proj<<<dim3(512), dim3(512), 0, stream>>>(x, Wfh, bf, Wgh, bg, Whh, bh, Q, K4, V8);
  k_rowmax<<<dim3(512), dim3(512), 0, stream>>>(Q, K4, M);
  k_attn<<<dim3(512), dim3(512), 0, stream>>>(Q, K4, V8, M, x, gamma, out);
}

// Round 7
// 163.512 us; speedup vs baseline: 1.1199x; 1.0263x over previous
//
#include <hip/hip_runtime.h>

typedef _Float16 half8 __attribute__((ext_vector_type(8)));
typedef _Float16 half4 __attribute__((ext_vector_type(4)));
typedef unsigned int uintx2 __attribute__((ext_vector_type(2)));
typedef unsigned int uintx4 __attribute__((ext_vector_type(4)));
typedef float floatx16 __attribute__((ext_vector_type(16)));

#define MFMA_F16(A, B, C) __builtin_amdgcn_mfma_f32_32x32x16_f16(A, B, C, 0, 0, 0)

constexpr int Bn = 4;     // batch
constexpr int Cc = 256;   // channels
constexpr int Cq = 32;    // C/8
constexpr int Nn = 4096;  // tokens (64*64)
constexpr float LOG2E = 1.44269504088896340736f;

// Layouts:
//   K4[b][cidx=0..3][n][8] : K fragment chunk cidx=(Cq>>3), dense across lanes
//   V8[b][nb=n>>3][c][8]   : V A-fragment, lane ml -> consecutive 16B chunks

__device__ inline floatx16 zero16() {
  floatx16 z;
#pragma unroll
  for (int i = 0; i < 16; ++i) z[i] = 0.f;
  return z;
}

__device__ inline unsigned int pkrtz(float a, float b) {
  return __builtin_bit_cast(unsigned int, __builtin_amdgcn_cvt_pkrtz(a, b));
}

// ---------------------------------------------------------------------------
// Kernel 0: W fp32 -> f16 (Wf scaled by log2e for exp2-domain softmax).
// ---------------------------------------------------------------------------
__global__ __launch_bounds__(256) void k_wconv(
    const float* __restrict__ Wf, const float* __restrict__ Wg,
    const float* __restrict__ Wh, _Float16* __restrict__ Wfh,
    _Float16* __restrict__ Wgh, _Float16* __restrict__ Whh) {
  int e = (blockIdx.x * 256 + threadIdx.x) * 4;
  const float* src;
  _Float16* dst;
  float sc = 1.f;
  if (e < 8192) { src = Wf + e; dst = Wfh + e; sc = LOG2E; }
  else if (e < 16384) { src = Wg + (e - 8192); dst = Wgh + (e - 8192); }
  else { src = Wh + (e - 16384); dst = Whh + (e - 16384); }
  float4 v = *(const float4*)src;
  half4 o;
  o[0] = (_Float16)(v.x * sc); o[1] = (_Float16)(v.y * sc);
  o[2] = (_Float16)(v.z * sc); o[3] = (_Float16)(v.w * sc);
  *(half4*)dst = o;
}

// ---------------------------------------------------------------------------
// Kernel 1: projections. Round-7 change: V8 stores routed through a PER-WAVE
// LDS transpose (vtr, stride-40 rows = 16B-aligned, h-halves bank-disjoint)
// -> 2 coalesced half8 global stores per lane instead of 16 scattered 2B
// stores (the V8 layout is token-inner; MFMA output is channel-inner).
// No barrier needed: each wave owns its vtr region; wave-internal DS
// ordering is guaranteed by lgkmcnt. Q/K4 stores already merge to 8B.
// ---------------------------------------------------------------------------
__global__ __launch_bounds__(512) void k_proj(
    const float* __restrict__ x,
    const _Float16* __restrict__ Wfh, const float* __restrict__ bf,
    const _Float16* __restrict__ Wgh, const float* __restrict__ bg,
    const _Float16* __restrict__ Whh, const float* __restrict__ bh,
    _Float16* __restrict__ Q, _Float16* __restrict__ K4,
    _Float16* __restrict__ V8) {
  __shared__ float xs[32][260];       // pad 260: 16B-aligned rows
  __shared__ _Float16 vtr[8][1280];   // per-wave V transpose scratch (2.5KB)
  int tid = threadIdx.x;
  int w = tid >> 6, lane = tid & 63;
  int ml = lane & 31, h = lane >> 5;
  int b = blockIdx.x >> 7, nt = blockIdx.x & 127;
  int n0 = nt * 32;

  // ---- stage x[b][0..255][n0..n0+31] transposed into xs[n_local][c] ----
  {
    int c = tid >> 3;          // 0..63
    int nl = (tid & 7) * 4;    // 4 consecutive tokens per thread
    const float* xp = x + (size_t)b * Cc * Nn + n0 + nl;
#pragma unroll
    for (int pass = 0; pass < 4; ++pass) {
      int cc = c + pass * 64;
      float4 v = *(const float4*)(xp + (size_t)cc * Nn);
      xs[nl + 0][cc] = v.x;
      xs[nl + 1][cc] = v.y;
      xs[nl + 2][cc] = v.z;
      xs[nl + 3][cc] = v.w;
    }
  }
  __syncthreads();

  // ---- build all 16 B-fragments once (lane ml = token n0+ml) ----
  half8 bfr[16];
#pragma unroll
  for (int kc = 0; kc < 16; ++kc) {
    const float* xp = &xs[ml][kc * 16 + h * 8];
    half8 f;
#pragma unroll
    for (int j = 0; j < 8; ++j) f[j] = (_Float16)xp[j];  // RTE
    bfr[kc] = f;
  }

  for (int t = w; t < 10; t += 8) {
    const _Float16* W;
    const float* bias;
    float bscale = 1.f;
    int o0 = 0;
    if (t == 0) { W = Wfh; bias = bf; bscale = LOG2E; }
    else if (t == 1) { W = Wgh; bias = bg; }
    else { W = Whh + (size_t)(t - 2) * 32 * Cc; bias = bh + (t - 2) * 32; o0 = (t - 2) * 32; }

    floatx16 acc = zero16();
    const _Float16* wp = W + (size_t)ml * Cc + h * 8;
#pragma unroll
    for (int kc = 0; kc < 16; ++kc) {
      half8 a = *(const half8*)(wp + kc * 16);
      acc = MFMA_F16(a, bfr[kc], acc);
    }

    if (t == 0) {
      // Q token-major Q[b][n][o]
      _Float16* op = Q + ((size_t)b * Nn + n0 + ml) * Cq;
#pragma unroll
      for (int qd = 0; qd < 4; ++qd) {
        float4 bq = *(const float4*)(bias + 8 * qd + 4 * h);
        const float* bqp = (const float*)&bq;
#pragma unroll
        for (int i = 0; i < 4; ++i) {
          int crow = i + 8 * qd + 4 * h;
          op[crow] = (_Float16)(acc[4 * qd + i] + bqp[i] * bscale);
        }
      }
    } else if (t == 1) {
      // K4[b][crow>>3][n][crow&7]
#pragma unroll
      for (int qd = 0; qd < 4; ++qd) {
        float4 bq = *(const float4*)(bias + 8 * qd + 4 * h);
        const float* bqp = (const float*)&bq;
#pragma unroll
        for (int i = 0; i < 4; ++i) {
          int crow = i + 8 * qd + 4 * h;
          K4[(((size_t)b * 4 + (crow >> 3)) * Nn + n0 + ml) * 8 + (crow & 7)] =
              (_Float16)(acc[4 * qd + i] + bqp[i]);
        }
      }
    } else {
      // V8 via per-wave LDS transpose -> coalesced half8 stores.
      // write: vtr[w][crow*40 + ml] (value for token n0+ml, channel o0+crow)
      _Float16* vs = vtr[w];
#pragma unroll
      for (int qd = 0; qd < 4; ++qd) {
        float4 bq = *(const float4*)(bias + 8 * qd + 4 * h);
        const float* bqp = (const float*)&bq;
#pragma unroll
        for (int i = 0; i < 4; ++i) {
          int crow = i + 8 * qd + 4 * h;
          vs[crow * 40 + ml] = (_Float16)(acc[4 * qd + i] + bqp[i]);
        }
      }
      // read: lane (ml,h) owns channel c=o0+ml, token-groups tg=h*2+{0,1}
      const _Float16* rs = vtr[w] + ml * 40;
#pragma unroll
      for (int r = 0; r < 2; ++r) {
        int tg = h * 2 + r;
        half8 vv = *(const half8*)(rs + tg * 8);
        *(half8*)(V8 + (((size_t)b * 512 + (n0 >> 3) + tg) * 256 + o0 + ml) * 8) = vv;
      }
    }
  }
}

// ---------------------------------------------------------------------------
// Kernel 2: pass-1 row max (log2-domain), K4 coalesced loads.
// MFMA bitwise identical to k_attn's S -> exp2(s-M) <= 1 exactly.
// ---------------------------------------------------------------------------
__global__ __launch_bounds__(512) void k_rowmax(const _Float16* __restrict__ Q,
                                                const _Float16* __restrict__ K4,
                                                float* __restrict__ M) {
  __shared__ float red[8][32];
  int tid = threadIdx.x, w = tid >> 6, lane = tid & 63;
  int ml = lane & 31, h = lane >> 5;
  int b = blockIdx.x >> 7, mt = blockIdx.x & 127;
  int m0 = mt * 32;
  const _Float16* qp = Q + ((size_t)b * Nn + m0 + ml) * Cq + h * 8;
  half8 qb0 = *(const half8*)(qp);
  half8 qb1 = *(const half8*)(qp + 16);
  const _Float16* kp0 = K4 + (((size_t)b * 4 + h) * Nn + w * 512 + ml) * 8;
  const _Float16* kp1 = K4 + (((size_t)b * 4 + 2 + h) * Nn + w * 512 + ml) * 8;
  float mx = -3.0e38f;
  for (int t = 0; t < 16; ++t) {
    floatx16 s = zero16();
    half8 k0 = *(const half8*)(kp0 + (size_t)t * 32 * 8);
    half8 k1 = *(const half8*)(kp1 + (size_t)t * 32 * 8);
    s = MFMA_F16(k0, qb0, s);
    s = MFMA_F16(k1, qb1, s);
#pragma unroll
    for (int i = 0; i < 16; ++i) mx = fmaxf(mx, s[i]);
  }
  mx = fmaxf(mx, __shfl_xor(mx, 32, 64));
  if (h == 0) red[w][ml] = mx;
  __syncthreads();
  if (tid < 32) {
    float m2 = red[0][tid];
#pragma unroll
    for (int i = 1; i < 8; ++i) m2 = fmaxf(m2, red[i][tid]);
    M[(size_t)b * Nn + m0 + tid] = m2;
  }
}

// ---------------------------------------------------------------------------
// O-tree helpers: per-wave O tile (256c x 32m f32) <-> LDS region (32KB).
// Layout: float2 index ((cb*8+rp)*2 + h)*32 + ml  (2-way bank = free).
// ---------------------------------------------------------------------------
__device__ inline void otree_write(float2* dst, const floatx16* o) {
#pragma unroll
  for (int cb = 0; cb < 8; ++cb)
#pragma unroll
    for (int rp = 0; rp < 8; ++rp)
      dst[(cb * 8 + rp) * 64] = make_float2(o[cb][2 * rp], o[cb][2 * rp + 1]);
}

__device__ inline void otree_add(const float2* src, floatx16* o) {
#pragma unroll
  for (int cb = 0; cb < 8; ++cb)
#pragma unroll
    for (int rp = 0; rp < 8; ++rp) {
      float2 v = src[(cb * 8 + rp) * 64];
      o[cb][2 * rp] += v.x;
      o[cb][2 * rp + 1] += v.y;
    }
}

// ---------------------------------------------------------------------------
// Kernel 3: attention -- round-4 main loop (proven best), round-7 change:
// O-tree uses 2 sequential 32KB regions instead of 4 (SAME summation tree
// => bitwise-identical output; 2 extra barriers). LDS 132KB -> 65KB, so a
// second block/CU can co-schedule IF the register file permits 4 waves/SIMD
// at ~232 regs/wave. launch_bounds kept (512,2): codegen untouched --
// occupancy is freed iff registers allow (this is the reg-pool diagnostic).
// ---------------------------------------------------------------------------
__global__ __launch_bounds__(512, 2) void k_attn(
    const _Float16* __restrict__ Q, const _Float16* __restrict__ K4,
    const _Float16* __restrict__ V8, const float* __restrict__ M,
    const float* __restrict__ xin, const float* __restrict__ gamma,
    float* __restrict__ out) {
  __shared__ float Ored[2 * 8192];   // 2 tree regions x 32KB (sequential tree)
  __shared__ float lred[8][32];
  int tid = threadIdx.x, w = tid >> 6, lane = tid & 63;
  int ml = lane & 31, h = lane >> 5;
  int bx = blockIdx.x;
  int mt = bx & 127, b = bx >> 7;
  int m0 = mt * 32;

  const _Float16* qp = Q + ((size_t)b * Nn + m0 + ml) * Cq + h * 8;
  half8 qb0 = *(const half8*)(qp);
  half8 qb1 = *(const half8*)(qp + 16);
  float Mv = M[(size_t)b * Nn + m0 + ml];
  float g = gamma[0];
  float lacc = 0.f;

  // K fragments: n = it*256 + w*32 + ml (coalesced across ml)
  const _Float16* k4b0 = K4 + (((size_t)b * 4 + h) * Nn + w * 32 + ml) * 8;
  const _Float16* k4b1 = K4 + (((size_t)b * 4 + 2 + h) * Nn + w * 32 + ml) * 8;
  // V8: nb = it*32 + w*4 + kc*2 + h ; element ((b*512+nb)*256 + c)*8
  const _Float16* v8b = V8 + (((size_t)b * 512 + w * 4 + h) * 256 + ml) * 8;

  floatx16 o[8];
#pragma unroll
  for (int i = 0; i < 8; ++i) o[i] = zero16();

  half8 k0 = *(const half8*)(k4b0);
  half8 k1 = *(const half8*)(k4b1);

  for (int it = 0; it < 16; ++it) {
    // ---- S: 32m x 32n for this wave's n-slice ----
    floatx16 s = zero16();
    s = MFMA_F16(k0, qb0, s);
    s = MFMA_F16(k1, qb1, s);
    // prefetch next iter's K (it=15 overruns into V8 region: benign)
    k0 = *(const half8*)(k4b0 + (size_t)(it + 1) * 2048);
    k1 = *(const half8*)(k4b1 + (size_t)(it + 1) * 2048);
    // ---- softmax numerator, in-register pack + half-swap ----
    float p[16];
#pragma unroll
    for (int i = 0; i < 16; ++i) p[i] = __builtin_amdgcn_exp2f(s[i] - Mv);
#pragma unroll
    for (int i = 0; i < 16; ++i) lacc += p[i];
    unsigned int c0 = pkrtz(p[0], p[1]),  c1 = pkrtz(p[2], p[3]);
    unsigned int c2 = pkrtz(p[4], p[5]),  c3 = pkrtz(p[6], p[7]);
    unsigned int c4 = pkrtz(p[8], p[9]),  c5 = pkrtz(p[10], p[11]);
    unsigned int c6 = pkrtz(p[12], p[13]), c7 = pkrtz(p[14], p[15]);
    // newD = [D(0:31) | S(0:31)], newS = [D(32:63) | S(32:63)]
    uintx2 t02 = __builtin_amdgcn_permlane32_swap(c0, c2, false, false);
    uintx2 t13 = __builtin_amdgcn_permlane32_swap(c1, c3, false, false);
    uintx2 t46 = __builtin_amdgcn_permlane32_swap(c4, c6, false, false);
    uintx2 t57 = __builtin_amdgcn_permlane32_swap(c5, c7, false, false);
    uintx4 f0v = {t02.x, t13.x, t02.y, t13.y};   // n-offsets  0..15 (k = h*8+j)
    uintx4 f1v = {t46.x, t57.x, t46.y, t57.y};   // n-offsets 16..31
    half8 pf0 = __builtin_bit_cast(half8, f0v);
    half8 pf1 = __builtin_bit_cast(half8, f1v);
    // ---- PV: all 256 channels for this n-slice ----
    const _Float16* vp = v8b + (size_t)it * 65536;  // 32 nb * 256c * 8
#pragma unroll
    for (int cb = 0; cb < 8; ++cb) {
      half8 vf0 = *(const half8*)(vp + cb * 256);
      o[cb] = MFMA_F16(vf0, pf0, o[cb]);
    }
#pragma unroll
    for (int cb = 0; cb < 8; ++cb) {
      half8 vf1 = *(const half8*)(vp + 4096 + cb * 256);
      o[cb] = MFMA_F16(vf1, pf1, o[cb]);
    }
  }

  // ---- l partials ----
  lacc += __shfl_xor(lacc, 32, 64);
  if (h == 0) lred[w][ml] = lacc;

  // ---- O reduction: sequential 2-region tree (same summation order as the
  //      4-region tree: w0+=w4, w1+=w5, w2+=w6, w3+=w7; w0+=w2, w1+=w3;
  //      w0+=w1 => bitwise-identical result) ----
  float2* Ored2 = (float2*)Ored;
  int lofs = h * 32 + ml;
  if (w == 4) otree_write(Ored2 + lofs, o);
  if (w == 5) otree_write(Ored2 + 4096 + lofs, o);
  __syncthreads();
  if (w == 0) otree_add(Ored2 + lofs, o);
  if (w == 1) otree_add(Ored2 + 4096 + lofs, o);
  __syncthreads();
  if (w == 6) otree_write(Ored2 + lofs, o);
  if (w == 7) otree_write(Ored2 + 4096 + lofs, o);
  __syncthreads();
  if (w == 2) otree_add(Ored2 + lofs, o);
  if (w == 3) otree_add(Ored2 + 4096 + lofs, o);
  __syncthreads();
  if (w == 2) otree_write(Ored2 + lofs, o);
  if (w == 3) otree_write(Ored2 + 4096 + lofs, o);
  __syncthreads();
  if (w == 0) otree_add(Ored2 + lofs, o);
  if (w == 1) otree_add(Ored2 + 4096 + lofs, o);
  __syncthreads();
  if (w == 1) otree_write(Ored2 + lofs, o);
  __syncthreads();
  if (w == 0) { otree_add(Ored2 + lofs, o); otree_write(Ored2 + lofs, o); }
  __syncthreads();

  // ---- fused epilogue: wave w handles channel block cb = w ----
  float lv = 0.f;
#pragma unroll
  for (int i = 0; i < 8; ++i) lv += lred[i][ml];
  float scale = g / lv;
  const float2* src = Ored2 + lofs;
  size_t obase = ((size_t)b * 256 + w * 32) * (size_t)Nn + m0 + ml;
#pragma unroll
  for (int rp = 0; rp < 8; ++rp) {
    float2 v = src[(w * 8 + rp) * 64];
    int r = 2 * rp;
    int cA = (r & 3) + 8 * (r >> 2) + 4 * h;
    size_t oa = obase + (size_t)cA * Nn;
    out[oa] = scale * v.x + xin[oa];
    out[oa + Nn] = scale * v.y + xin[oa + Nn];
  }
}

// ---------------------------------------------------------------------------
extern "C" void kernel_launch(void* const* d_in, const int* in_sizes, int n_in,
                              void* d_out, int out_size, void* d_ws,
                              size_t ws_size, hipStream_t stream) {
  const float* x = (const float*)d_in[0];
  const float* Wf = (const float*)d_in[1];
  const float* bf = (const float*)d_in[2];
  const float* Wg = (const float*)d_in[3];
  const float* bg = (const float*)d_in[4];
  const float* Wh = (const float*)d_in[5];
  const float* bh = (const float*)d_in[6];
  const float* gamma = (const float*)d_in[7];
  float* out = (float*)d_out;

  char* ws = (char*)d_ws;
  // Layout (bytes):
  //   Q      [0,        1048576)
  //   K4     [1048576,  2097152)
  //   V8     [2097152, 10485760)
  //   M      [10485760, 10551296)
  //   Wfh    [10551296, 10567680)
  //   Wgh    [10567680, 10584064)
  //   Whh    [10584064, 10715136)
  _Float16* Q  = (_Float16*)(ws);
  _Float16* K4 = (_Float16*)(ws + 1048576);
  _Float16* V8 = (_Float16*)(ws + 2097152);
  float*    M  = (float*)   (ws + 10485760);
  _Float16* Wfh = (_Float16*)(ws + 10551296);
  _Float16* Wgh = (_Float16*)(ws + 10567680);
  _Float16* Whh = (_Float16*)(ws + 10584064);

  k_wconv<<<dim3(80), dim3(256), 0, stream>>>(Wf, Wg, Wh, Wfh, Wgh, Whh);
  k_proj<<<dim3(512), dim3(512), 0, stream>>>(x, Wfh, bf, Wgh, bg, Whh, bh, Q, K4, V8);
  k_rowmax<<<dim3(512), dim3(512), 0, stream>>>(Q, K4, M);
  k_attn<<<dim3(512), dim3(512), 0, stream>>>(Q, K4, V8, M, x, gamma, out);
}

// Round 8
// 156.968 us; speedup vs baseline: 1.1666x; 1.0417x over previous
//
#include <hip/hip_runtime.h>

typedef _Float16 half8 __attribute__((ext_vector_type(8)));
typedef _Float16 half4 __attribute__((ext_vector_type(4)));
typedef unsigned int uintx2 __attribute__((ext_vector_type(2)));
typedef unsigned int uintx4 __attribute__((ext_vector_type(4)));
typedef float floatx16 __attribute__((ext_vector_type(16)));

#define MFMA_F16(A, B, C) __builtin_amdgcn_mfma_f32_32x32x16_f16(A, B, C, 0, 0, 0)

constexpr int Bn = 4;     // batch
constexpr int Cc = 256;   // channels
constexpr int Cq = 32;    // C/8
constexpr int Nn = 4096;  // tokens (64*64)
constexpr float LOG2E = 1.44269504088896340736f;

// Layouts:
//   K4[b][cidx=0..3][n][8] : K fragment chunk cidx=(Cq>>3), dense across lanes
//   V8[b][nb=n>>3][c][8]   : V A-fragment, lane ml -> consecutive 16B chunks

__device__ inline floatx16 zero16() {
  floatx16 z;
#pragma unroll
  for (int i = 0; i < 16; ++i) z[i] = 0.f;
  return z;
}

__device__ inline unsigned int pkrtz(float a, float b) {
  return __builtin_bit_cast(unsigned int, __builtin_amdgcn_cvt_pkrtz(a, b));
}

// ---------------------------------------------------------------------------
// Kernel 0: W fp32 -> f16 (Wf scaled by log2e for exp2-domain softmax).
// ---------------------------------------------------------------------------
__global__ __launch_bounds__(256) void k_wconv(
    const float* __restrict__ Wf, const float* __restrict__ Wg,
    const float* __restrict__ Wh, _Float16* __restrict__ Wfh,
    _Float16* __restrict__ Wgh, _Float16* __restrict__ Whh) {
  int e = (blockIdx.x * 256 + threadIdx.x) * 4;
  const float* src;
  _Float16* dst;
  float sc = 1.f;
  if (e < 8192) { src = Wf + e; dst = Wfh + e; sc = LOG2E; }
  else if (e < 16384) { src = Wg + (e - 8192); dst = Wgh + (e - 8192); }
  else { src = Wh + (e - 16384); dst = Whh + (e - 16384); }
  float4 v = *(const float4*)src;
  half4 o;
  o[0] = (_Float16)(v.x * sc); o[1] = (_Float16)(v.y * sc);
  o[2] = (_Float16)(v.z * sc); o[3] = (_Float16)(v.w * sc);
  *(half4*)dst = o;
}

// ---------------------------------------------------------------------------
// Kernel 1: projections (unchanged from round 7: LDS-staged x, per-wave V8
// LDS transpose -> coalesced half8 stores).
// ---------------------------------------------------------------------------
__global__ __launch_bounds__(512) void k_proj(
    const float* __restrict__ x,
    const _Float16* __restrict__ Wfh, const float* __restrict__ bf,
    const _Float16* __restrict__ Wgh, const float* __restrict__ bg,
    const _Float16* __restrict__ Whh, const float* __restrict__ bh,
    _Float16* __restrict__ Q, _Float16* __restrict__ K4,
    _Float16* __restrict__ V8) {
  __shared__ float xs[32][260];       // pad 260: 16B-aligned rows
  __shared__ _Float16 vtr[8][1280];   // per-wave V transpose scratch (2.5KB)
  int tid = threadIdx.x;
  int w = tid >> 6, lane = tid & 63;
  int ml = lane & 31, h = lane >> 5;
  int b = blockIdx.x >> 7, nt = blockIdx.x & 127;
  int n0 = nt * 32;

  // ---- stage x[b][0..255][n0..n0+31] transposed into xs[n_local][c] ----
  {
    int c = tid >> 3;          // 0..63
    int nl = (tid & 7) * 4;    // 4 consecutive tokens per thread
    const float* xp = x + (size_t)b * Cc * Nn + n0 + nl;
#pragma unroll
    for (int pass = 0; pass < 4; ++pass) {
      int cc = c + pass * 64;
      float4 v = *(const float4*)(xp + (size_t)cc * Nn);
      xs[nl + 0][cc] = v.x;
      xs[nl + 1][cc] = v.y;
      xs[nl + 2][cc] = v.z;
      xs[nl + 3][cc] = v.w;
    }
  }
  __syncthreads();

  // ---- build all 16 B-fragments once (lane ml = token n0+ml) ----
  half8 bfr[16];
#pragma unroll
  for (int kc = 0; kc < 16; ++kc) {
    const float* xp = &xs[ml][kc * 16 + h * 8];
    half8 f;
#pragma unroll
    for (int j = 0; j < 8; ++j) f[j] = (_Float16)xp[j];  // RTE
    bfr[kc] = f;
  }

  for (int t = w; t < 10; t += 8) {
    const _Float16* W;
    const float* bias;
    float bscale = 1.f;
    int o0 = 0;
    if (t == 0) { W = Wfh; bias = bf; bscale = LOG2E; }
    else if (t == 1) { W = Wgh; bias = bg; }
    else { W = Whh + (size_t)(t - 2) * 32 * Cc; bias = bh + (t - 2) * 32; o0 = (t - 2) * 32; }

    floatx16 acc = zero16();
    const _Float16* wp = W + (size_t)ml * Cc + h * 8;
#pragma unroll
    for (int kc = 0; kc < 16; ++kc) {
      half8 a = *(const half8*)(wp + kc * 16);
      acc = MFMA_F16(a, bfr[kc], acc);
    }

    if (t == 0) {
      // Q token-major Q[b][n][o]
      _Float16* op = Q + ((size_t)b * Nn + n0 + ml) * Cq;
#pragma unroll
      for (int qd = 0; qd < 4; ++qd) {
        float4 bq = *(const float4*)(bias + 8 * qd + 4 * h);
        const float* bqp = (const float*)&bq;
#pragma unroll
        for (int i = 0; i < 4; ++i) {
          int crow = i + 8 * qd + 4 * h;
          op[crow] = (_Float16)(acc[4 * qd + i] + bqp[i] * bscale);
        }
      }
    } else if (t == 1) {
      // K4[b][crow>>3][n][crow&7]
#pragma unroll
      for (int qd = 0; qd < 4; ++qd) {
        float4 bq = *(const float4*)(bias + 8 * qd + 4 * h);
        const float* bqp = (const float*)&bq;
#pragma unroll
        for (int i = 0; i < 4; ++i) {
          int crow = i + 8 * qd + 4 * h;
          K4[(((size_t)b * 4 + (crow >> 3)) * Nn + n0 + ml) * 8 + (crow & 7)] =
              (_Float16)(acc[4 * qd + i] + bqp[i]);
        }
      }
    } else {
      // V8 via per-wave LDS transpose -> coalesced half8 stores.
      _Float16* vs = vtr[w];
#pragma unroll
      for (int qd = 0; qd < 4; ++qd) {
        float4 bq = *(const float4*)(bias + 8 * qd + 4 * h);
        const float* bqp = (const float*)&bq;
#pragma unroll
        for (int i = 0; i < 4; ++i) {
          int crow = i + 8 * qd + 4 * h;
          vs[crow * 40 + ml] = (_Float16)(acc[4 * qd + i] + bqp[i]);
        }
      }
      const _Float16* rs = vtr[w] + ml * 40;
#pragma unroll
      for (int r = 0; r < 2; ++r) {
        int tg = h * 2 + r;
        half8 vv = *(const half8*)(rs + tg * 8);
        *(half8*)(V8 + (((size_t)b * 512 + (n0 >> 3) + tg) * 256 + o0 + ml) * 8) = vv;
      }
    }
  }
}

// ---------------------------------------------------------------------------
// Kernel 2: pass-1 row max (log2-domain), K4 coalesced loads.
// MFMA bitwise identical to k_attn's S -> exp2(s-M) <= 1 exactly.
// ---------------------------------------------------------------------------
__global__ __launch_bounds__(512) void k_rowmax(const _Float16* __restrict__ Q,
                                                const _Float16* __restrict__ K4,
                                                float* __restrict__ M) {
  __shared__ float red[8][32];
  int tid = threadIdx.x, w = tid >> 6, lane = tid & 63;
  int ml = lane & 31, h = lane >> 5;
  int b = blockIdx.x >> 7, mt = blockIdx.x & 127;
  int m0 = mt * 32;
  const _Float16* qp = Q + ((size_t)b * Nn + m0 + ml) * Cq + h * 8;
  half8 qb0 = *(const half8*)(qp);
  half8 qb1 = *(const half8*)(qp + 16);
  const _Float16* kp0 = K4 + (((size_t)b * 4 + h) * Nn + w * 512 + ml) * 8;
  const _Float16* kp1 = K4 + (((size_t)b * 4 + 2 + h) * Nn + w * 512 + ml) * 8;
  float mx = -3.0e38f;
  for (int t = 0; t < 16; ++t) {
    floatx16 s = zero16();
    half8 k0 = *(const half8*)(kp0 + (size_t)t * 32 * 8);
    half8 k1 = *(const half8*)(kp1 + (size_t)t * 32 * 8);
    s = MFMA_F16(k0, qb0, s);
    s = MFMA_F16(k1, qb1, s);
#pragma unroll
    for (int i = 0; i < 16; ++i) mx = fmaxf(mx, s[i]);
  }
  mx = fmaxf(mx, __shfl_xor(mx, 32, 64));
  if (h == 0) red[w][ml] = mx;
  __syncthreads();
  if (tid < 32) {
    float m2 = red[0][tid];
#pragma unroll
    for (int i = 1; i < 8; ++i) m2 = fmaxf(m2, red[i][tid]);
    M[(size_t)b * Nn + m0 + tid] = m2;
  }
}

// ---------------------------------------------------------------------------
// O-tree helpers: per-wave O tile (256c x 32m f32) <-> LDS region (32KB).
// Layout: float2 index ((cb*8+rp)*2 + h)*32 + ml  (2-way bank = free).
// ---------------------------------------------------------------------------
__device__ inline void otree_write(float2* dst, const floatx16* o) {
#pragma unroll
  for (int cb = 0; cb < 8; ++cb)
#pragma unroll
    for (int rp = 0; rp < 8; ++rp)
      dst[(cb * 8 + rp) * 64] = make_float2(o[cb][2 * rp], o[cb][2 * rp + 1]);
}

__device__ inline void otree_add(const float2* src, floatx16* o) {
#pragma unroll
  for (int cb = 0; cb < 8; ++cb)
#pragma unroll
    for (int rp = 0; rp < 8; ++rp) {
      float2 v = src[(cb * 8 + rp) * 64];
      o[cb][2 * rp] += v.x;
      o[cb][2 * rp + 1] += v.y;
    }
}

// ---------------------------------------------------------------------------
// Kernel 3: attention, round-8: 64 m-rows per block (grid 256 = 1 block/CU).
// 8 waves = 2 m-halves (mh) x 4 n-ways (nw). Wave: 32m x 256c acc (o[8],
// same as round-4), 32 iters at n-stride 128. The two mh waves of each nw
// read the SAME V tile ~concurrently -> L1 hits; total L2 V-traffic halves
// vs round-7 (this kernel is L2-BW-bound: each block streams the whole
// per-batch V slice; FETCH=46MB but L2 reads were ~1.3GB).
// S MFMA operand order identical to k_rowmax => exp2(s-M) <= 1 invariant.
// Two independent 4-way O-trees (one per mh), fused epilogue.
// ---------------------------------------------------------------------------
__global__ __launch_bounds__(512, 2) void k_attn(
    const _Float16* __restrict__ Q, const _Float16* __restrict__ K4,
    const _Float16* __restrict__ V8, const float* __restrict__ M,
    const float* __restrict__ xin, const float* __restrict__ gamma,
    float* __restrict__ out) {
  __shared__ float Ored[4 * 8192];   // 4 regions x 32KB: {mh0: 0,1} {mh1: 2,3}
  __shared__ float lred[8][32];
  int tid = threadIdx.x, w = tid >> 6, lane = tid & 63;
  int ml = lane & 31, h = lane >> 5;
  int mh = w >> 2, nw = w & 3;
  int bx = blockIdx.x;
  int mt = bx & 63, b = bx >> 6;     // grid 256 = 4b x 64mt
  int mb = mt * 64;
  int m0 = mb + mh * 32;

  const _Float16* qp = Q + ((size_t)b * Nn + m0 + ml) * Cq + h * 8;
  half8 qb0 = *(const half8*)(qp);
  half8 qb1 = *(const half8*)(qp + 16);
  float Mv = M[(size_t)b * Nn + m0 + ml];
  float g = gamma[0];
  float lacc = 0.f;

  // K fragments: n = it*128 + nw*32 + ml (coalesced across ml)
  const _Float16* k4b0 = K4 + (((size_t)b * 4 + h) * Nn + nw * 32 + ml) * 8;
  const _Float16* k4b1 = K4 + (((size_t)b * 4 + 2 + h) * Nn + nw * 32 + ml) * 8;
  // V8: nb = it*16 + nw*4 + kc*2 + h ; element ((b*512+nb)*256 + c)*8
  const _Float16* v8b = V8 + (((size_t)b * 512 + nw * 4 + h) * 256 + ml) * 8;

  floatx16 o[8];
#pragma unroll
  for (int i = 0; i < 8; ++i) o[i] = zero16();

  half8 k0 = *(const half8*)(k4b0);
  half8 k1 = *(const half8*)(k4b1);

  for (int it = 0; it < 32; ++it) {
    // ---- S: 32m x 32n for this wave's n-slice ----
    floatx16 s = zero16();
    s = MFMA_F16(k0, qb0, s);
    s = MFMA_F16(k1, qb1, s);
    // prefetch next iter's K (it=31 overruns into V8 region: benign)
    k0 = *(const half8*)(k4b0 + (size_t)(it + 1) * 1024);
    k1 = *(const half8*)(k4b1 + (size_t)(it + 1) * 1024);
    // ---- softmax numerator, in-register pack + half-swap ----
    float p[16];
#pragma unroll
    for (int i = 0; i < 16; ++i) p[i] = __builtin_amdgcn_exp2f(s[i] - Mv);
#pragma unroll
    for (int i = 0; i < 16; ++i) lacc += p[i];
    unsigned int c0 = pkrtz(p[0], p[1]),  c1 = pkrtz(p[2], p[3]);
    unsigned int c2 = pkrtz(p[4], p[5]),  c3 = pkrtz(p[6], p[7]);
    unsigned int c4 = pkrtz(p[8], p[9]),  c5 = pkrtz(p[10], p[11]);
    unsigned int c6 = pkrtz(p[12], p[13]), c7 = pkrtz(p[14], p[15]);
    // newD = [D(0:31) | S(0:31)], newS = [D(32:63) | S(32:63)]
    uintx2 t02 = __builtin_amdgcn_permlane32_swap(c0, c2, false, false);
    uintx2 t13 = __builtin_amdgcn_permlane32_swap(c1, c3, false, false);
    uintx2 t46 = __builtin_amdgcn_permlane32_swap(c4, c6, false, false);
    uintx2 t57 = __builtin_amdgcn_permlane32_swap(c5, c7, false, false);
    uintx4 f0v = {t02.x, t13.x, t02.y, t13.y};   // n-offsets  0..15 (k = h*8+j)
    uintx4 f1v = {t46.x, t57.x, t46.y, t57.y};   // n-offsets 16..31
    half8 pf0 = __builtin_bit_cast(half8, f0v);
    half8 pf1 = __builtin_bit_cast(half8, f1v);
    // ---- PV: all 256 channels for this n-slice ----
    const _Float16* vp = v8b + (size_t)it * 32768;  // 16 nb * 256c * 8
#pragma unroll
    for (int cb = 0; cb < 8; ++cb) {
      half8 vf0 = *(const half8*)(vp + cb * 256);
      o[cb] = MFMA_F16(vf0, pf0, o[cb]);
    }
#pragma unroll
    for (int cb = 0; cb < 8; ++cb) {
      half8 vf1 = *(const half8*)(vp + 4096 + cb * 256);
      o[cb] = MFMA_F16(vf1, pf1, o[cb]);
    }
  }

  // ---- l partials ----
  lacc += __shfl_xor(lacc, 32, 64);
  if (h == 0) lred[w][ml] = lacc;

  // ---- O reduction: two independent 4-way trees (regions mh*2, mh*2+1) ----
  float2* Ored2 = (float2*)Ored;
  int lofs = h * 32 + ml;
  float2* rg0 = Ored2 + (size_t)(mh * 2) * 4096 + lofs;
  float2* rg1 = Ored2 + (size_t)(mh * 2 + 1) * 4096 + lofs;
  if (nw == 2) otree_write(rg0, o);
  if (nw == 3) otree_write(rg1, o);
  __syncthreads();
  if (nw == 0) otree_add(rg0, o);
  if (nw == 1) otree_add(rg1, o);
  __syncthreads();
  if (nw == 1) otree_write(rg1, o);
  __syncthreads();
  if (nw == 0) { otree_add(rg1, o); otree_write(rg0, o); }
  __syncthreads();
  // final sums: region mh*2 holds full O for m-half mh

  // ---- fused epilogue: wave w handles channel block w*32, both m-halves ----
  float lv0 = lred[0][ml] + lred[1][ml] + lred[2][ml] + lred[3][ml];
  float lv1 = lred[4][ml] + lred[5][ml] + lred[6][ml] + lred[7][ml];
  float sc0 = g / lv0;
  float sc1 = g / lv1;
  const float2* src0 = Ored2 + lofs;               // mh0 region 0
  const float2* src1 = Ored2 + (size_t)2 * 4096 + lofs;  // mh1 region 2
  size_t obase0 = ((size_t)b * 256 + w * 32) * (size_t)Nn + mb + ml;
  size_t obase1 = obase0 + 32;
#pragma unroll
  for (int rp = 0; rp < 8; ++rp) {
    int r = 2 * rp;
    int cA = (r & 3) + 8 * (r >> 2) + 4 * h;
    size_t oa0 = obase0 + (size_t)cA * Nn;
    size_t oa1 = obase1 + (size_t)cA * Nn;
    float2 v0 = src0[(w * 8 + rp) * 64];
    float2 v1 = src1[(w * 8 + rp) * 64];
    out[oa0] = sc0 * v0.x + xin[oa0];
    out[oa0 + Nn] = sc0 * v0.y + xin[oa0 + Nn];
    out[oa1] = sc1 * v1.x + xin[oa1];
    out[oa1 + Nn] = sc1 * v1.y + xin[oa1 + Nn];
  }
}

// ---------------------------------------------------------------------------
extern "C" void kernel_launch(void* const* d_in, const int* in_sizes, int n_in,
                              void* d_out, int out_size, void* d_ws,
                              size_t ws_size, hipStream_t stream) {
  const float* x = (const float*)d_in[0];
  const float* Wf = (const float*)d_in[1];
  const float* bf = (const float*)d_in[2];
  const float* Wg = (const float*)d_in[3];
  const float* bg = (const float*)d_in[4];
  const float* Wh = (const float*)d_in[5];
  const float* bh = (const float*)d_in[6];
  const float* gamma = (const float*)d_in[7];
  float* out = (float*)d_out;

  char* ws = (char*)d_ws;
  // Layout (bytes):
  //   Q      [0,        1048576)
  //   K4     [1048576,  2097152)
  //   V8     [2097152, 10485760)
  //   M      [10485760, 10551296)
  //   Wfh    [10551296, 10567680)
  //   Wgh    [10567680, 10584064)
  //   Whh    [10584064, 10715136)
  _Float16* Q  = (_Float16*)(ws);
  _Float16* K4 = (_Float16*)(ws + 1048576);
  _Float16* V8 = (_Float16*)(ws + 2097152);
  float*    M  = (float*)   (ws + 10485760);
  _Float16* Wfh = (_Float16*)(ws + 10551296);
  _Float16* Wgh = (_Float16*)(ws + 10567680);
  _Float16* Whh = (_Float16*)(ws + 10584064);

  k_wconv<<<dim3(80), dim3(256), 0, stream>>>(Wf, Wg, Wh, Wfh, Wgh, Whh);
  k_proj<<<dim3(512), dim3(512), 0, stream>>>(x, Wfh, bf, Wgh, bg, Whh, bh, Q, K4, V8);
  k_rowmax<<<dim3(512), dim3(512), 0, stream>>>(Q, K4, M);
  k_attn<<<dim3(256), dim3(512), 0, stream>>>(Q, K4, V8, M, x, gamma, out);
}

// Round 10
// 151.588 us; speedup vs baseline: 1.2080x; 1.0355x over previous
//
#include <hip/hip_runtime.h>

typedef _Float16 half8 __attribute__((ext_vector_type(8)));
typedef _Float16 half4 __attribute__((ext_vector_type(4)));
typedef unsigned int uintx2 __attribute__((ext_vector_type(2)));
typedef unsigned int uintx4 __attribute__((ext_vector_type(4)));
typedef float floatx16 __attribute__((ext_vector_type(16)));

#define MFMA_F16(A, B, C) __builtin_amdgcn_mfma_f32_32x32x16_f16(A, B, C, 0, 0, 0)

constexpr int Bn = 4;     // batch
constexpr int Cc = 256;   // channels
constexpr int Cq = 32;    // C/8
constexpr int Nn = 4096;  // tokens (64*64)
constexpr float LOG2E = 1.44269504088896340736f;

// Layouts:
//   K4[b][cidx=0..3][n][8] : K fragment chunk cidx=(Cq>>3), dense across lanes
//   V8[b][nb=n>>3][c][8]   : now holds f16(x) -- PV computes O_x = x·P^T;
//                            Wh applied per-block in k_attn epilogue:
//                            out = Wh·(x·A^T) + bh  (softmax rows sum to 1)

__device__ inline floatx16 zero16() {
  floatx16 z;
#pragma unroll
  for (int i = 0; i < 16; ++i) z[i] = 0.f;
  return z;
}

__device__ inline unsigned int pkrtz(float a, float b) {
  return __builtin_bit_cast(unsigned int, __builtin_amdgcn_cvt_pkrtz(a, b));
}

// ---------------------------------------------------------------------------
// Kernel 0: W fp32 -> f16 (Wf scaled by log2e for exp2-domain softmax).
// ---------------------------------------------------------------------------
__global__ __launch_bounds__(256) void k_wconv(
    const float* __restrict__ Wf, const float* __restrict__ Wg,
    const float* __restrict__ Wh, _Float16* __restrict__ Wfh,
    _Float16* __restrict__ Wgh, _Float16* __restrict__ Whh) {
  int e = (blockIdx.x * 256 + threadIdx.x) * 4;
  const float* src;
  _Float16* dst;
  float sc = 1.f;
  if (e < 8192) { src = Wf + e; dst = Wfh + e; sc = LOG2E; }
  else if (e < 16384) { src = Wg + (e - 8192); dst = Wgh + (e - 8192); }
  else { src = Wh + (e - 16384); dst = Whh + (e - 16384); }
  float4 v = *(const float4*)src;
  half4 o;
  o[0] = (_Float16)(v.x * sc); o[1] = (_Float16)(v.y * sc);
  o[2] = (_Float16)(v.z * sc); o[3] = (_Float16)(v.w * sc);
  *(half4*)dst = o;
}

// ---------------------------------------------------------------------------
// Kernel 1 (round-9): Q/K projections + V8 = f16(x) layout transform.
// The h-GEMM (8 of 10 tiles, with its strided W gather + 16-deep MFMA
// chains) is GONE -- Wh is applied in k_attn's epilogue instead.
// Waves 0,1 compute Q,K tiles; then ALL threads convert the staged x tile
// into V8 (2 half8 groups per thread, coalesced stores).
// ---------------------------------------------------------------------------
__global__ __launch_bounds__(512) void k_qkv(
    const float* __restrict__ x,
    const _Float16* __restrict__ Wfh, const float* __restrict__ bf,
    const _Float16* __restrict__ Wgh, const float* __restrict__ bg,
    _Float16* __restrict__ Q, _Float16* __restrict__ K4,
    _Float16* __restrict__ V8) {
  __shared__ float xs[32][260];  // pad 260: 16B-aligned rows
  int tid = threadIdx.x;
  int w = tid >> 6, lane = tid & 63;
  int ml = lane & 31, h = lane >> 5;
  int b = blockIdx.x >> 7, nt = blockIdx.x & 127;
  int n0 = nt * 32;

  // ---- stage x[b][0..255][n0..n0+31] transposed into xs[n_local][c] ----
  {
    int c = tid >> 3;          // 0..63
    int nl = (tid & 7) * 4;    // 4 consecutive tokens per thread
    const float* xp = x + (size_t)b * Cc * Nn + n0 + nl;
#pragma unroll
    for (int pass = 0; pass < 4; ++pass) {
      int cc = c + pass * 64;
      float4 v = *(const float4*)(xp + (size_t)cc * Nn);
      xs[nl + 0][cc] = v.x;
      xs[nl + 1][cc] = v.y;
      xs[nl + 2][cc] = v.z;
      xs[nl + 3][cc] = v.w;
    }
  }
  __syncthreads();

  if (w < 2) {
    // ---- build 16 B-fragments (lane ml = token n0+ml) ----
    half8 bfr[16];
#pragma unroll
    for (int kc = 0; kc < 16; ++kc) {
      const float* xp = &xs[ml][kc * 16 + h * 8];
      half8 f;
#pragma unroll
      for (int j = 0; j < 8; ++j) f[j] = (_Float16)xp[j];  // RTE
      bfr[kc] = f;
    }

    const _Float16* W = (w == 0) ? Wfh : Wgh;
    const float* bias = (w == 0) ? bf : bg;
    float bscale = (w == 0) ? LOG2E : 1.f;

    floatx16 acc = zero16();
    const _Float16* wp = W + (size_t)ml * Cc + h * 8;
#pragma unroll
    for (int kc = 0; kc < 16; ++kc) {
      half8 a = *(const half8*)(wp + kc * 16);
      acc = MFMA_F16(a, bfr[kc], acc);
    }

    if (w == 0) {
      // Q token-major Q[b][n][o]
      _Float16* op = Q + ((size_t)b * Nn + n0 + ml) * Cq;
#pragma unroll
      for (int qd = 0; qd < 4; ++qd) {
        float4 bq = *(const float4*)(bias + 8 * qd + 4 * h);
        const float* bqp = (const float*)&bq;
#pragma unroll
        for (int i = 0; i < 4; ++i) {
          int crow = i + 8 * qd + 4 * h;
          op[crow] = (_Float16)(acc[4 * qd + i] + bqp[i] * bscale);
        }
      }
    } else {
      // K4[b][crow>>3][n][crow&7]
#pragma unroll
      for (int qd = 0; qd < 4; ++qd) {
        float4 bq = *(const float4*)(bias + 8 * qd + 4 * h);
        const float* bqp = (const float*)&bq;
#pragma unroll
        for (int i = 0; i < 4; ++i) {
          int crow = i + 8 * qd + 4 * h;
          K4[(((size_t)b * 4 + (crow >> 3)) * Nn + n0 + ml) * 8 + (crow & 7)] =
              (_Float16)(acc[4 * qd + i] + bqp[i]);
        }
      }
    }
  }

  // ---- V8 = f16(x) transpose-convert: group g = (nbl, c), 2 per thread ----
#pragma unroll
  for (int gi = 0; gi < 2; ++gi) {
    int gidx = tid + gi * 512;          // 0..1023
    int nbl = gidx >> 8, c = gidx & 255;
    half8 vv;
#pragma unroll
    for (int i = 0; i < 8; ++i) vv[i] = (_Float16)xs[nbl * 8 + i][c];
    *(half8*)(V8 + (((size_t)b * 512 + (n0 >> 3) + nbl) * 256 + c) * 8) = vv;
  }
}

// ---------------------------------------------------------------------------
// Kernel 2: pass-1 row max (log2-domain), K4 coalesced loads.
// MFMA bitwise identical to k_attn's S -> exp2(s-M) <= 1 exactly.
// ---------------------------------------------------------------------------
__global__ __launch_bounds__(512) void k_rowmax(const _Float16* __restrict__ Q,
                                                const _Float16* __restrict__ K4,
                                                float* __restrict__ M) {
  __shared__ float red[8][32];
  int tid = threadIdx.x, w = tid >> 6, lane = tid & 63;
  int ml = lane & 31, h = lane >> 5;
  int b = blockIdx.x >> 7, mt = blockIdx.x & 127;
  int m0 = mt * 32;
  const _Float16* qp = Q + ((size_t)b * Nn + m0 + ml) * Cq + h * 8;
  half8 qb0 = *(const half8*)(qp);
  half8 qb1 = *(const half8*)(qp + 16);
  const _Float16* kp0 = K4 + (((size_t)b * 4 + h) * Nn + w * 512 + ml) * 8;
  const _Float16* kp1 = K4 + (((size_t)b * 4 + 2 + h) * Nn + w * 512 + ml) * 8;
  float mx = -3.0e38f;
  for (int t = 0; t < 16; ++t) {
    floatx16 s = zero16();
    half8 k0 = *(const half8*)(kp0 + (size_t)t * 32 * 8);
    half8 k1 = *(const half8*)(kp1 + (size_t)t * 32 * 8);
    s = MFMA_F16(k0, qb0, s);
    s = MFMA_F16(k1, qb1, s);
#pragma unroll
    for (int i = 0; i < 16; ++i) mx = fmaxf(mx, s[i]);
  }
  mx = fmaxf(mx, __shfl_xor(mx, 32, 64));
  if (h == 0) red[w][ml] = mx;
  __syncthreads();
  if (tid < 32) {
    float m2 = red[0][tid];
#pragma unroll
    for (int i = 1; i < 8; ++i) m2 = fmaxf(m2, red[i][tid]);
    M[(size_t)b * Nn + m0 + tid] = m2;
  }
}

// ---------------------------------------------------------------------------
// O-tree helpers: per-wave O tile (256c x 32m f32) <-> LDS region (32KB).
// Layout: float2 index ((cb*8+rp)*2 + h)*32 + ml  (2-way bank = free).
// ---------------------------------------------------------------------------
__device__ inline void otree_write(float2* dst, const floatx16* o) {
#pragma unroll
  for (int cb = 0; cb < 8; ++cb)
#pragma unroll
    for (int rp = 0; rp < 8; ++rp)
      dst[(cb * 8 + rp) * 64] = make_float2(o[cb][2 * rp], o[cb][2 * rp + 1]);
}

__device__ inline void otree_add(const float2* src, floatx16* o) {
#pragma unroll
  for (int cb = 0; cb < 8; ++cb)
#pragma unroll
    for (int rp = 0; rp < 8; ++rp) {
      float2 v = src[(cb * 8 + rp) * 64];
      o[cb][2 * rp] += v.x;
      o[cb][2 * rp + 1] += v.y;
    }
}

// ---------------------------------------------------------------------------
// Kernel 3: attention (round-9). Main loop = round-8 exactly (64m blocks,
// 2mh x 4nw waves, in-register P hand-off, V8 now = f16(x)).
// NEW epilogue: per-wave 32x64 output tile of the fused Wh-GEMM:
//   out[c,m] = Wh[c,:]·(O_x[:,m]·g/l) + g·bh[c] + x[c,m]
// B-fragments read from the O-tree LDS via the closed-form inverse of the
// writer layout: float addr = kq*512 + off(j,h,ml),
//   off = (rb>>1)*128 + hw*64 + 2*ml + (rb&1), rb=(u&3)|((u>>3)<<2),
//   hw=(u>>2)&1, u=h*8+j.  (g/l folded into B; bias exact since sum A = 1.)
// ---------------------------------------------------------------------------
__global__ __launch_bounds__(512, 2) void k_attn(
    const _Float16* __restrict__ Q, const _Float16* __restrict__ K4,
    const _Float16* __restrict__ V8, const float* __restrict__ M,
    const _Float16* __restrict__ Whh, const float* __restrict__ bh,
    const float* __restrict__ xin, const float* __restrict__ gamma,
    float* __restrict__ out) {
  __shared__ float Ored[4 * 8192];   // 4 regions x 32KB: {mh0: 0,1} {mh1: 2,3}
  __shared__ float lred[8][32];
  int tid = threadIdx.x, w = tid >> 6, lane = tid & 63;
  int ml = lane & 31, h = lane >> 5;
  int mh = w >> 2, nw = w & 3;
  int bx = blockIdx.x;
  int mt = bx & 63, b = bx >> 6;     // grid 256 = 4b x 64mt
  int mb = mt * 64;
  int m0 = mb + mh * 32;

  const _Float16* qp = Q + ((size_t)b * Nn + m0 + ml) * Cq + h * 8;
  half8 qb0 = *(const half8*)(qp);
  half8 qb1 = *(const half8*)(qp + 16);
  float Mv = M[(size_t)b * Nn + m0 + ml];
  float g = gamma[0];
  float lacc = 0.f;

  // K fragments: n = it*128 + nw*32 + ml (coalesced across ml)
  const _Float16* k4b0 = K4 + (((size_t)b * 4 + h) * Nn + nw * 32 + ml) * 8;
  const _Float16* k4b1 = K4 + (((size_t)b * 4 + 2 + h) * Nn + nw * 32 + ml) * 8;
  // V8: nb = it*16 + nw*4 + kc*2 + h ; element ((b*512+nb)*256 + c)*8
  const _Float16* v8b = V8 + (((size_t)b * 512 + nw * 4 + h) * 256 + ml) * 8;

  floatx16 o[8];
#pragma unroll
  for (int i = 0; i < 8; ++i) o[i] = zero16();

  half8 k0 = *(const half8*)(k4b0);
  half8 k1 = *(const half8*)(k4b1);

  for (int it = 0; it < 32; ++it) {
    // ---- S: 32m x 32n for this wave's n-slice ----
    floatx16 s = zero16();
    s = MFMA_F16(k0, qb0, s);
    s = MFMA_F16(k1, qb1, s);
    // prefetch next iter's K (it=31 overruns into V8 region: benign)
    k0 = *(const half8*)(k4b0 + (size_t)(it + 1) * 1024);
    k1 = *(const half8*)(k4b1 + (size_t)(it + 1) * 1024);
    // ---- softmax numerator, in-register pack + half-swap ----
    float p[16];
#pragma unroll
    for (int i = 0; i < 16; ++i) p[i] = __builtin_amdgcn_exp2f(s[i] - Mv);
#pragma unroll
    for (int i = 0; i < 16; ++i) lacc += p[i];
    unsigned int c0 = pkrtz(p[0], p[1]),  c1 = pkrtz(p[2], p[3]);
    unsigned int c2 = pkrtz(p[4], p[5]),  c3 = pkrtz(p[6], p[7]);
    unsigned int c4 = pkrtz(p[8], p[9]),  c5 = pkrtz(p[10], p[11]);
    unsigned int c6 = pkrtz(p[12], p[13]), c7 = pkrtz(p[14], p[15]);
    // newD = [D(0:31) | S(0:31)], newS = [D(32:63) | S(32:63)]
    uintx2 t02 = __builtin_amdgcn_permlane32_swap(c0, c2, false, false);
    uintx2 t13 = __builtin_amdgcn_permlane32_swap(c1, c3, false, false);
    uintx2 t46 = __builtin_amdgcn_permlane32_swap(c4, c6, false, false);
    uintx2 t57 = __builtin_amdgcn_permlane32_swap(c5, c7, false, false);
    uintx4 f0v = {t02.x, t13.x, t02.y, t13.y};   // n-offsets  0..15 (k = h*8+j)
    uintx4 f1v = {t46.x, t57.x, t46.y, t57.y};   // n-offsets 16..31
    half8 pf0 = __builtin_bit_cast(half8, f0v);
    half8 pf1 = __builtin_bit_cast(half8, f1v);
    // ---- PV: all 256 channels (of x) for this n-slice ----
    const _Float16* vp = v8b + (size_t)it * 32768;  // 16 nb * 256c * 8
#pragma unroll
    for (int cb = 0; cb < 8; ++cb) {
      half8 vf0 = *(const half8*)(vp + cb * 256);
      o[cb] = MFMA_F16(vf0, pf0, o[cb]);
    }
#pragma unroll
    for (int cb = 0; cb < 8; ++cb) {
      half8 vf1 = *(const half8*)(vp + 4096 + cb * 256);
      o[cb] = MFMA_F16(vf1, pf1, o[cb]);
    }
  }

  // ---- l partials ----
  lacc += __shfl_xor(lacc, 32, 64);
  if (h == 0) lred[w][ml] = lacc;

  // ---- O reduction: two independent 4-way trees (regions mh*2, mh*2+1) ----
  float2* Ored2 = (float2*)Ored;
  int lofs = h * 32 + ml;
  float2* rg0 = Ored2 + (size_t)(mh * 2) * 4096 + lofs;
  float2* rg1 = Ored2 + (size_t)(mh * 2 + 1) * 4096 + lofs;
  if (nw == 2) otree_write(rg0, o);
  if (nw == 3) otree_write(rg1, o);
  __syncthreads();
  if (nw == 0) otree_add(rg0, o);
  if (nw == 1) otree_add(rg1, o);
  __syncthreads();
  if (nw == 1) otree_write(rg1, o);
  __syncthreads();
  if (nw == 0) { otree_add(rg1, o); otree_write(rg0, o); }
  __syncthreads();
  // region 0 holds full O_x for mh0; region 2 for mh1 (f32, 256k x 32m)

  // ---- fused Wh-GEMM epilogue: wave w -> out channels c0..c0+31, 64 m ----
  float lv0 = lred[0][ml] + lred[1][ml] + lred[2][ml] + lred[3][ml];
  float lv1 = lred[4][ml] + lred[5][ml] + lred[6][ml] + lred[7][ml];
  float il0 = g / lv0;               // fold gamma into the B-scale
  float il1 = g / lv1;
  int offs[8];
#pragma unroll
  for (int j = 0; j < 8; ++j) {
    int u = h * 8 + j;
    int rb = (u & 3) | ((u >> 3) << 2);
    int hw = (u >> 2) & 1;
    offs[j] = (rb >> 1) * 128 + hw * 64 + 2 * ml + (rb & 1);
  }
  const float* R0 = Ored;                 // mh0 (region 0)
  const float* R1 = Ored + 2 * 8192;      // mh1 (region 2)
  int c0 = w * 32;
  const _Float16* whp = Whh + (size_t)(c0 + ml) * 256 + h * 8;
  floatx16 d0 = zero16(), d1 = zero16();
#pragma unroll
  for (int kq = 0; kq < 16; ++kq) {
    half8 a = *(const half8*)(whp + kq * 16);
    float q0[8], q1[8];
#pragma unroll
    for (int j = 0; j < 8; ++j) {
      q0[j] = R0[kq * 512 + offs[j]] * il0;
      q1[j] = R1[kq * 512 + offs[j]] * il1;
    }
    uintx4 b0v = {pkrtz(q0[0], q0[1]), pkrtz(q0[2], q0[3]),
                  pkrtz(q0[4], q0[5]), pkrtz(q0[6], q0[7])};
    uintx4 b1v = {pkrtz(q1[0], q1[1]), pkrtz(q1[2], q1[3]),
                  pkrtz(q1[4], q1[5]), pkrtz(q1[6], q1[7])};
    d0 = MFMA_F16(a, __builtin_bit_cast(half8, b0v), d0);
    d1 = MFMA_F16(a, __builtin_bit_cast(half8, b1v), d1);
  }

  // ---- store: out = D + g*bh[c] + x ----
  size_t ob = (size_t)b * 256 * (size_t)Nn;
#pragma unroll
  for (int r = 0; r < 16; ++r) {
    int c = c0 + (r & 3) + 8 * (r >> 2) + 4 * h;
    float bias = g * bh[c];
    size_t oa0 = ob + (size_t)c * Nn + mb + ml;
    size_t oa1 = oa0 + 32;
    out[oa0] = d0[r] + bias + xin[oa0];
    out[oa1] = d1[r] + bias + xin[oa1];
  }
}

// ---------------------------------------------------------------------------
extern "C" void kernel_launch(void* const* d_in, const int* in_sizes, int n_in,
                              void* d_out, int out_size, void* d_ws,
                              size_t ws_size, hipStream_t stream) {
  const float* x = (const float*)d_in[0];
  const float* Wf = (const float*)d_in[1];
  const float* bf = (const float*)d_in[2];
  const float* Wg = (const float*)d_in[3];
  const float* bg = (const float*)d_in[4];
  const float* Wh = (const float*)d_in[5];
  const float* bh = (const float*)d_in[6];
  const float* gamma = (const float*)d_in[7];
  float* out = (float*)d_out;

  char* ws = (char*)d_ws;
  // Layout (bytes):
  //   Q      [0,        1048576)
  //   K4     [1048576,  2097152)
  //   V8     [2097152, 10485760)
  //   M      [10485760, 10551296)
  //   Wfh    [10551296, 10567680)
  //   Wgh    [10567680, 10584064)
  //   Whh    [10584064, 10715136)
  _Float16* Q  = (_Float16*)(ws);
  _Float16* K4 = (_Float16*)(ws + 1048576);
  _Float16* V8 = (_Float16*)(ws + 2097152);
  float*    M  = (float*)   (ws + 10485760);
  _Float16* Wfh = (_Float16*)(ws + 10551296);
  _Float16* Wgh = (_Float16*)(ws + 10567680);
  _Float16* Whh = (_Float16*)(ws + 10584064);

  k_wconv<<<dim3(80), dim3(256), 0, stream>>>(Wf, Wg, Wh, Wfh, Wgh, Whh);
  k_qkv<<<dim3(512), dim3(512), 0, stream>>>(x, Wfh, bf, Wgh, bg, Q, K4, V8);
  k_rowmax<<<dim3(512), dim3(512), 0, stream>>>(Q, K4, M);
  k_attn<<<dim3(256), dim3(512), 0, stream>>>(Q, K4, V8, M, Whh, bh, x, gamma, out);
}